// Round 9
// baseline (718.426 us; speedup 1.0000x reference)
//
#include <hip/hip_runtime.h>
#include <hip/hip_bf16.h>
#include <math.h>
#include <stdint.h>

#define B_   2
#define T_   1024
#define HID_ 2048
#define H_   16
#define DK_  128
#define DV_  128
#define TS_  16     // timesteps staged per LDS tile in recurrence

typedef __bf16 bf16;
typedef __attribute__((ext_vector_type(8))) __bf16 bf16x8;
typedef __attribute__((ext_vector_type(4))) float f32x4;
typedef __attribute__((ext_vector_type(2))) float f32x2;

typedef __attribute__((address_space(3))) uint32_t* lds_ptr_t;
typedef const __attribute__((address_space(1))) uint32_t* glb_ptr_t;

__device__ __forceinline__ float sigmoidf_(float x) {
    return 1.0f / (1.0f + __expf(-x));
}

// async global->LDS, 16B per lane. LDS base wave-uniform (HW: lane i ->
// base + 16*i); global address is per-lane.
__device__ __forceinline__ void ldg_to_lds16(const void* g, void* lds) {
    __builtin_amdgcn_global_load_lds((glb_ptr_t)(uintptr_t)g,
                                     (lds_ptr_t)(uintptr_t)lds, 16, 0, 0);
}

// DPP rotate-add via builtin (compiler handles the VALU->DPP wait-state
// hazard; raw inline-asm v_add_f32_dpp does NOT and corrupts data --
// measured in v10). CTRL = 0x120 + n (row_ror:n).
template <int CTRL>
__device__ __forceinline__ float dpp_ror_add(float x) {
    int yi = __builtin_amdgcn_update_dpp(
        0, __builtin_bit_cast(int, x), CTRL, 0xF, 0xF, true);
    return x + __builtin_bit_cast(float, yi);
}
// all-reduce (sum) across the 16 lanes of a DPP row
__device__ __forceinline__ float row16_allreduce(float x) {
    x = dpp_ror_add<0x128>(x);   // ror 8
    x = dpp_ror_add<0x124>(x);   // ror 4
    x = dpp_ror_add<0x122>(x);   // ror 2
    x = dpp_ror_add<0x121>(x);   // ror 1
    return x;
}

// ---------------------------------------------------------------------------
// prep_kernel: ALL input preprocessing in ONE launch (kills ~13 launch gaps).
// Flat-block-id segments (branch is uniform per block):
//   [0,2048)        x fp32 -> bf16 cast (8 elems/thread)
//   [2048,20480)    12 transpose-cast segments (32x32 tiles)
//   [20480,20608)   skinny3: bb/bd/lam = x @ {Wbb,Wbd,Wlam}
// NOTE: wcat/wgate/woT live in their OWN workspace region (v12 aliased them
// into wqkvT, which is only legal with sequential reuse -- race, ERRATA).
// ---------------------------------------------------------------------------
__device__ __forceinline__ void tile_tcast(
    float (*tile)[33], const float* __restrict__ W, bf16* __restrict__ Wt,
    int N, int ldout, int noff, int koff, float sign, int bx, int by, int tid)
{
    const int k0 = by * 32, n0 = bx * 32;
    const int r = tid >> 5, c = tid & 31;
    #pragma unroll
    for (int i = 0; i < 4; ++i)
        tile[r + 8 * i][c] = W[(size_t)(k0 + r + 8 * i) * N + n0 + c];
    __syncthreads();
    #pragma unroll
    for (int i = 0; i < 4; ++i)
        Wt[(size_t)(noff + n0 + r + 8 * i) * ldout + koff + k0 + c] =
            (bf16)(sign * tile[c][r + 8 * i]);
}

__global__ __launch_bounds__(256) void prep_kernel(
    const float* __restrict__ x, bf16* __restrict__ xb,
    const float* __restrict__ Wq, const float* __restrict__ Wk,
    const float* __restrict__ Wv, const float* __restrict__ Wgb1,
    const float* __restrict__ Wgd1, const float* __restrict__ Wg1,
    const float* __restrict__ Wg2, const float* __restrict__ Wo,
    const float* __restrict__ Wgb2, const float* __restrict__ Wgd2,
    bf16* __restrict__ wqkvT, bf16* __restrict__ wgate, bf16* __restrict__ woT,
    bf16* __restrict__ wcat,
    const float* __restrict__ Wbb, const float* __restrict__ Wbd,
    const float* __restrict__ Wlam,
    float* __restrict__ bb, float* __restrict__ bd, float* __restrict__ lam)
{
    __shared__ float tile[32][33];
    __shared__ float xs[16][128];
    __shared__ float wsh[128][48];

    const int bid = blockIdx.x;
    const int tid = threadIdx.x;

    if (bid < 2048) {                       // ---- x cast ----
        int i = bid * 256 + tid;
        float4 a = ((const float4*)x)[2 * i];
        float4 b = ((const float4*)x)[2 * i + 1];
        bf16x8 o;
        o[0] = (bf16)a.x; o[1] = (bf16)a.y; o[2] = (bf16)a.z; o[3] = (bf16)a.w;
        o[4] = (bf16)b.x; o[5] = (bf16)b.y; o[6] = (bf16)b.z; o[7] = (bf16)b.w;
        ((bf16x8*)xb)[i] = o;
        return;
    }
    if (bid < 20480) {                      // ---- transpose-cast segments ----
        int local;
        const float* src; bf16* dst; int N, ldout, noff = 0, koff = 0, nx;
        float sign = 1.0f;
        if      (bid < 6144)  { local = bid - 2048;  src = Wq;   dst = wqkvT;                       N = 2048; ldout = 2048; nx = 64; }
        else if (bid < 10240) { local = bid - 6144;  src = Wk;   dst = wqkvT + (size_t)2048 * 2048; N = 2048; ldout = 2048; nx = 64; }
        else if (bid < 14336) { local = bid - 10240; src = Wv;   dst = wqkvT + (size_t)4096 * 2048; N = 2048; ldout = 2048; nx = 64; }
        else if (bid < 14592) { local = bid - 14336; src = Wgb1; dst = wqkvT + (size_t)6144 * 2048; N = 128;  ldout = 2048; nx = 4;  }
        else if (bid < 14848) { local = bid - 14592; src = Wgd1; dst = wqkvT + (size_t)6272 * 2048; N = 128;  ldout = 2048; nx = 4;  }
        else if (bid < 15104) { local = bid - 14848; src = Wg1;  dst = wqkvT + (size_t)6400 * 2048; N = 128;  ldout = 2048; nx = 4;  }
        else if (bid < 15360) { local = bid - 15104; src = Wg2;  dst = wgate; N = 2048; ldout = 128; nx = 64; }
        else if (bid < 19456) { local = bid - 15360; src = Wo;   dst = woT;   N = 2048; ldout = 2048; nx = 64; }
        else if (bid < 19712) { local = bid - 19456; src = Wgb2; dst = wcat; N = 2048; ldout = 256; noff = 0;    koff = 0;   nx = 64; }
        else if (bid < 19968) { local = bid - 19712; src = Wgd2; dst = wcat; N = 2048; ldout = 256; noff = 0;    koff = 128; nx = 64; }
        else if (bid < 20224) { local = bid - 19968; src = Wgb2; dst = wcat; N = 2048; ldout = 256; noff = 2048; koff = 0;   nx = 64; }
        else                  { local = bid - 20224; src = Wgd2; dst = wcat; N = 2048; ldout = 256; noff = 2048; koff = 128; sign = -1.0f; nx = 64; }
        tile_tcast(tile, src, dst, N, ldout, noff, koff, sign, local % nx, local / nx, tid);
        return;
    }
    // ---- skinny3 ----
    {
        const int m0 = (bid - 20480) * 16;
        const int r = tid >> 4, cg = tid & 15;
        float acc0 = 0.f, acc1 = 0.f, acc2 = 0.f;
        for (int k0 = 0; k0 < HID_; k0 += 128) {
            __syncthreads();
            #pragma unroll
            for (int i = 0; i < 2; ++i) {
                int f = tid + 256 * i;
                int rr = f >> 5, cc = (f & 31) * 4;
                *(float4*)&xs[rr][cc] = *(const float4*)(x + (size_t)(m0 + rr) * HID_ + k0 + cc);
            }
            #pragma unroll
            for (int i = 0; i < 2; ++i) {
                int f = tid + 256 * i;
                int kk = f >> 2, cc = (f & 3) * 4;
                *(float4*)&wsh[kk][cc]      = *(const float4*)(Wbb  + (size_t)(k0 + kk) * 16 + cc);
                *(float4*)&wsh[kk][16 + cc] = *(const float4*)(Wbd  + (size_t)(k0 + kk) * 16 + cc);
                *(float4*)&wsh[kk][32 + cc] = *(const float4*)(Wlam + (size_t)(k0 + kk) * 16 + cc);
            }
            __syncthreads();
            #pragma unroll 8
            for (int kk = 0; kk < 128; ++kk) {
                float xv = xs[r][kk];
                acc0 += xv * wsh[kk][cg];
                acc1 += xv * wsh[kk][16 + cg];
                acc2 += xv * wsh[kk][32 + cg];
            }
        }
        size_t o = (size_t)(m0 + r) * 16 + cg;
        bb[o] = acc0; bd[o] = acc1; lam[o] = acc2;
    }
}

// ---------------------------------------------------------------------------
// bf16 MFMA GEMM: C[M,N] = A[M,K] @ Bt[N,K]^T (+bias). 128x128 tile, BK=32.
// lda/ldc = element row strides of A/C; Bt row stride = Kfull.
// decay_epi: apply x <- exp(-exp(A_log[h]) * softplus(x + dtb[c])) in the
// epilogue (fuses the former decay_gate kernel; c = col&2047, h = c>>7).
// XCD-aware block swizzle (T1) when grid %8 == 0.
// ---------------------------------------------------------------------------
__global__ __launch_bounds__(256) void mfma_gemm_kernel(
    const bf16* __restrict__ A, const bf16* __restrict__ Bt,
    const float* __restrict__ bias, void* __restrict__ Cout,
    int M, int N, int Kfull, int lda, int ldc,
    const float* __restrict__ alog, const float* __restrict__ dtb,
    int decay_epi)
{
    __shared__ bf16 As[128 * 32];
    __shared__ bf16 Bs[128 * 32];

    const int tid  = threadIdx.x;
    const int w    = tid >> 6;
    const int lane = tid & 63;

    // XCD swizzle: contiguous tile chunk per XCD (bijective when nwg%8==0)
    const int gx  = gridDim.x;
    const int nwg = gx * gridDim.y;
    int f = blockIdx.y * gx + blockIdx.x;
    if ((nwg & 7) == 0) { int q = nwg >> 3; f = (f & 7) * q + (f >> 3); }
    const int n0 = (f % gx) * 128;
    const int m0 = (f / gx) * 128;

    const int wm = (w >> 1) * 64;
    const int wn = (w & 1) * 64;

    const int lr = lane >> 2;
    const int lc = (lane & 3) * 8;

    f32x4 acc[4][4];
    #pragma unroll
    for (int i = 0; i < 4; ++i)
        #pragma unroll
        for (int j = 0; j < 4; ++j) acc[i][j] = (f32x4)0.0f;

    const bf16* ApL = As + (wm + (lane & 15)) * 32 + (lane >> 4) * 8;
    const bf16* BpL = Bs + (wn + (lane & 15)) * 32 + (lane >> 4) * 8;

    for (int k0 = 0; k0 < Kfull; k0 += 32) {
        #pragma unroll
        for (int i = 0; i < 2; ++i) {
            const int rr = (w * 2 + i) * 16 + lr;
            ldg_to_lds16(A  + (size_t)(m0 + rr) * lda   + k0 + lc, As + (w * 2 + i) * 512);
            ldg_to_lds16(Bt + (size_t)(n0 + rr) * Kfull + k0 + lc, Bs + (w * 2 + i) * 512);
        }
        __syncthreads();

        bf16x8 af[4], bfr[4];
        #pragma unroll
        for (int i = 0; i < 4; ++i) af[i]  = *(const bf16x8*)(ApL + i * 16 * 32);
        #pragma unroll
        for (int j = 0; j < 4; ++j) bfr[j] = *(const bf16x8*)(BpL + j * 16 * 32);
        #pragma unroll
        for (int i = 0; i < 4; ++i)
            #pragma unroll
            for (int j = 0; j < 4; ++j)
                acc[i][j] = __builtin_amdgcn_mfma_f32_16x16x32_bf16(
                    af[i], bfr[j], acc[i][j], 0, 0, 0);
        __syncthreads();
    }

    float* Cf = (float*)Cout;
    #pragma unroll
    for (int i = 0; i < 4; ++i) {
        const int row = m0 + wm + i * 16 + (lane >> 4) * 4;
        #pragma unroll
        for (int j = 0; j < 4; ++j) {
            const int col = n0 + wn + j * 16 + (lane & 15);
            if (decay_epi) {
                const int c  = col & (HID_ - 1);
                const int hh = c >> 7;
                const float na = -__expf(alog[hh]);
                const float db = dtb[c];
                #pragma unroll
                for (int r = 0; r < 4; ++r) {
                    float xv = acc[i][j][r] + db;
                    float sp = (xv > 20.0f) ? xv : log1pf(__expf(xv));
                    Cf[(size_t)(row + r) * ldc + col] = __expf(na * sp);
                }
            } else {
                const float bv = bias ? bias[col] : 0.0f;
                #pragma unroll
                for (int r = 0; r < 4; ++r)
                    Cf[(size_t)(row + r) * ldc + col] = acc[i][j][r] + bv;
            }
        }
    }
}

// ---------------------------------------------------------------------------
// Fused conv(q)+conv(k)+conv(v)+midcast in one launch.
//   [0,2048)    conv q: coloff 0,    mode 2 (l2norm * DK^-0.5)
//   [2048,4096) conv k: coloff 2048, mode 1 (l2norm)
//   [4096,6144) conv v: coloff 4096, mode 0
//   [6144,6912) midcast: cols 6144..6527 of [M,6528] -> bf16 midb [M,384]
// ---------------------------------------------------------------------------
__device__ __forceinline__ void conv_body(
    float (*red)[8], const float* __restrict__ xin, int ldx, int coloff,
    const float* __restrict__ w, float* __restrict__ yout, int mode,
    int bt, int tid)
{
    const int t = bt & (T_ - 1);
    const float* xr = xin + (size_t)bt * ldx + coloff;

    float val[8];
    #pragma unroll
    for (int jj = 0; jj < 8; ++jj) {
        int c = tid + 256 * jj;
        float4 wc = *(const float4*)(w + (size_t)c * 4);
        const float* xc = xr + c;
        float acc = wc.w * xc[0];
        if (t >= 1) acc += wc.z * xc[-ldx];
        if (t >= 2) acc += wc.y * xc[-2 * ldx];
        if (t >= 3) acc += wc.x * xc[-3 * ldx];
        val[jj] = acc * sigmoidf_(acc);
    }

    if (mode > 0) {
        const int wv = tid >> 6;
        #pragma unroll
        for (int jj = 0; jj < 8; ++jj) {
            float v2 = val[jj] * val[jj];
            #pragma unroll
            for (int m = 1; m < 64; m <<= 1) v2 += __shfl_xor(v2, m);
            if ((tid & 63) == 0) red[wv][jj] = v2;
        }
        __syncthreads();
        const int wb = (tid >> 7) * 2;
        #pragma unroll
        for (int jj = 0; jj < 8; ++jj) {
            float ss = red[wb][jj] + red[wb + 1][jj];
            float sc = rsqrtf(ss + 1e-6f);
            if (mode == 2) sc *= 0.08838834764831845f;     // DK^-0.5
            val[jj] *= sc;
        }
    }

    const size_t row = (size_t)bt * HID_;
    #pragma unroll
    for (int jj = 0; jj < 8; ++jj)
        yout[row + tid + 256 * jj] = val[jj];
}

__global__ __launch_bounds__(256) void convmid_kernel(
    const float* __restrict__ xin,
    const float* __restrict__ wq, const float* __restrict__ wk,
    const float* __restrict__ wv,
    float* __restrict__ bufQ, float* __restrict__ bufK,
    float* __restrict__ bufV, bf16* __restrict__ midb)
{
    __shared__ float red[4][8];
    const int bid = blockIdx.x;
    const int tid = threadIdx.x;
    if (bid < 2048)      conv_body(red, xin, 6528, 0,    wq, bufQ, 2, bid,        tid);
    else if (bid < 4096) conv_body(red, xin, 6528, 2048, wk, bufK, 1, bid - 2048, tid);
    else if (bid < 6144) conv_body(red, xin, 6528, 4096, wv, bufV, 0, bid - 4096, tid);
    else {
        int i = (bid - 6144) * 256 + tid;   // over 2048*96
        int m = i / 96, c4 = i - m * 96;
        float4 v = *(const float4*)(xin + (size_t)m * 6528 + 6144 + c4 * 4);
        bf16 o[4] = {(bf16)v.x, (bf16)v.y, (bf16)v.z, (bf16)v.w};
        *(uint64_t*)(midb + (size_t)m * 384 + c4 * 4) = *(uint64_t*)o;
    }
}

// ---------------------------------------------------------------------------
// Dual-state gated delta-rule recurrence, v11 (passing, ~210us): v6
// structure + bv premultiply + u = fma(-bt, p, bv). Builtin DPP reduces.
// Grid: 512 blocks x 256 thr: bx = sv*32 + bh; bh = b*16+h, sv = s*8+vc.
// Block: 4 waves; wave = 4 cols x 16 ksegs (8 k-chan each).
// LDS slot layout per row (128 floats): slot l<16 holds channels 8l..8l+3,
// slot l>=16 holds 8(l-16)+4..8(l-16)+7  -> each b128 read is 2-way/bank.
// ---------------------------------------------------------------------------
struct StepRegs {
    float4 e0, e1, k0, k1, q0, q1;
    float bt, bv;
};

__global__ __launch_bounds__(256) void fkda_kernel(
    const float* __restrict__ qp, const float* __restrict__ kp,
    const float* __restrict__ vp, const float* __restrict__ egf,
    const float* __restrict__ egs, int ldeg,
    const float* __restrict__ bbp, const float* __restrict__ bdp,
    float* __restrict__ ofp, float* __restrict__ osp)
{
    const int bx = blockIdx.x;
    const int bh = bx & 31;
    const int sv = bx >> 5;
    const int b  = bh >> 4;
    const int h  = bh & 15;
    const int s  = sv >> 3;
    const int vc = sv & 7;

    const float* eg = s ? egs : egf;
    float*       op = s ? osp : ofp;
    const float  bsign = s ? -1.0f : 1.0f;

    const int tid  = threadIdx.x;
    const int lane = tid & 63;
    const int w    = tid >> 6;
    const int kseg = lane & 15;
    const int colb = w * 4 + (lane >> 4);

    const size_t base  = (size_t)b * T_ * HID_ + (size_t)h * DK_;
    const size_t baseg = (size_t)b * T_ * ldeg + (size_t)h * DK_;
    const size_t ocol  = base + (size_t)vc * 16 + colb;

    __shared__ float EG[2][TS_ * 128];     // 8 KB each buf
    __shared__ float KK[2][TS_ * 128];
    __shared__ float QQ[2][TS_ * 128];
    __shared__ float VV[2][TS_ * 16];
    __shared__ float BT[2][TS_];

    f32x2 S0 = {0.f, 0.f}, S1 = {0.f, 0.f}, S2 = {0.f, 0.f}, S3 = {0.f, 0.f};

    // staging lane map: flat word W = n*256 + 4*lane must hold row tt's
    // swizzled slot; lane fetches the matching global channel.
    const int l5  = lane & 31;
    const int ttl = lane >> 5;
    const int cg  = (l5 < 16) ? (l5 * 8) : ((l5 - 16) * 8 + 4);
    const int sl  = kseg * 4;    // read slot word base

    // issue all async global->LDS staging for the tile starting at t0
    auto stage_glds = [&](int bi, int t0) {
        #pragma unroll
        for (int i = 0; i < 2; ++i) {
            int n  = w * 2 + i;
            int tt = n * 2 + ttl;
            size_t rq = base  + (size_t)(t0 + tt) * HID_ + cg;
            size_t rg = baseg + (size_t)(t0 + tt) * ldeg + cg;
            ldg_to_lds16(eg + rg, &EG[bi][n * 256]);
            ldg_to_lds16(kp + rq, &KK[bi][n * 256]);
            ldg_to_lds16(qp + rq, &QQ[bi][n * 256]);
        }
        if (tid < 64) {       // V: 16t x 16cols fp32, lane l -> tt=l>>2
            int tt2 = tid >> 2, vo = (tid & 3) * 4;
            size_t g = base + (size_t)(t0 + tt2) * HID_ + vc * 16 + vo;
            ldg_to_lds16(vp + g, &VV[bi][0]);
        }
    };

    // ---- prologue: stage tile 0 (incl. beta) ----
    float bbv = 0.0f, bdv = 0.0f;
    if (tid < TS_) {
        size_t gi = ((size_t)b * T_ + tid) * H_ + h;
        bbv = bbp[gi]; bdv = bdp[gi];
    }
    stage_glds(0, 0);
    if (tid < TS_) BT[0][tid] = sigmoidf_(bbv + bsign * bdv);

    float ooPrev = 0.0f;       // held output element from previous tile

    for (int t0 = 0; t0 < T_; t0 += TS_) {
        const int cur = (t0 >> 4) & 1;
        const int nxt = cur ^ 1;
        const bool more = (t0 + TS_) < T_;

        __syncthreads();    // buf[cur] staged (vmcnt drained) + prev compute done

        // issue next tile's staging; flies under this tile's compute
        if (more) {
            stage_glds(nxt, t0 + TS_);
            if (tid < TS_) {
                size_t gi = ((size_t)b * T_ + t0 + TS_ + tid) * H_ + h;
                bbv = bbp[gi]; bdv = bdp[gi];
            }
        }

        // store previous tile's output element (ack hides under compute)
        if (t0) op[ocol + (size_t)(t0 - TS_ + kseg) * HID_] = ooPrev;

        const float* Eb = &EG[cur][sl];
        const float* Kb = &KK[cur][sl];
        const float* Qb = &QQ[cur][sl];
        const float* Vc = &VV[cur][colb];
        const float* Bc = &BT[cur][0];

        float oo = 0.0f;

        auto ldstep = [&](StepRegs& R, int tt) {
            const float* Ep = Eb + tt * 128;
            const float* Kp = Kb + tt * 128;
            const float* Qp = Qb + tt * 128;
            R.e0 = *(const float4*)(Ep);
            R.e1 = *(const float4*)(Ep + 64);
            R.k0 = *(const float4*)(Kp);
            R.k1 = *(const float4*)(Kp + 64);
            R.q0 = *(const float4*)(Qp);
            R.q1 = *(const float4*)(Qp + 64);
            R.bt = Bc[tt];
            R.bv = R.bt * Vc[tt * 16];
        };

        auto compute = [&](const StepRegs& R, int tt) {
            f32x2 e0 = {R.e0.x, R.e0.y}, e1 = {R.e0.z, R.e0.w};
            f32x2 e2 = {R.e1.x, R.e1.y}, e3 = {R.e1.z, R.e1.w};
            f32x2 k0 = {R.k0.x, R.k0.y}, k1 = {R.k0.z, R.k0.w};
            f32x2 k2 = {R.k1.x, R.k1.y}, k3 = {R.k1.z, R.k1.w};
            f32x2 q0 = {R.q0.x, R.q0.y}, q1 = {R.q0.z, R.q0.w};
            f32x2 q2 = {R.q1.x, R.q1.y}, q3 = {R.q1.z, R.q1.w};

            S0 *= e0; S1 *= e1; S2 *= e2; S3 *= e3;
            f32x2 pa = k0 * S0 + k1 * S1;
            f32x2 pb = k2 * S2 + k3 * S3;
            f32x2 ps = pa + pb;
            float p = row16_allreduce(ps.x + ps.y);

            float u = fmaf(-R.bt, p, R.bv);
            f32x2 u2 = {u, u};
            S0 += k0 * u2; S1 += k1 * u2; S2 += k2 * u2; S3 += k3 * u2;
            f32x2 oa = q0 * S0 + q1 * S1;
            f32x2 ob = q2 * S2 + q3 * S3;
            f32x2 om = oa + ob;
            float o = row16_allreduce(om.x + om.y);

            oo = (tt == kseg) ? o : oo;   // keep own timestep's value
        };

        // ---- 16 steps, 2-deep register pipeline (named sets A/B) ----
        StepRegs RA, RB;
        ldstep(RA, 0);
        #pragma unroll
        for (int tp = 0; tp < TS_; tp += 2) {
            ldstep(RB, tp + 1);
            compute(RA, tp);
            if (tp + 2 < TS_) ldstep(RA, tp + 2);
            compute(RB, tp + 1);
        }

        ooPrev = oo;

        // next tile's beta (loads long since landed; write before barrier)
        if (more && tid < TS_) BT[nxt][tid] = sigmoidf_(bbv + bsign * bdv);
    }

    // epilogue: store last tile's outputs
    op[ocol + (size_t)(T_ - TS_ + kseg) * HID_] = ooPrev;
}

// ---------------------------------------------------------------------------
// o = lam*o_f + (1-lam)*o_s -> per-head RMSNorm * onorm_w -> * sigmoid(gate)
// ---------------------------------------------------------------------------
__global__ __launch_bounds__(256) void mix_norm_gate_kernel(
    const float* of, const float* os, const float* lam_pre,
    const float* gate, const float* onorm_w, bf16* outp)
{
    const int bt  = blockIdx.x;
    const int tid = threadIdx.x;
    const size_t row = (size_t)bt * HID_;

    float val[8];
    #pragma unroll
    for (int jj = 0; jj < 8; ++jj) {
        int c = tid + 256 * jj;
        int h = c >> 7;
        float l = sigmoidf_(lam_pre[(size_t)bt * H_ + h]);
        val[jj] = l * of[row + c] + (1.0f - l) * os[row + c];
    }

    __shared__ float red[4][8];
    const int wv = tid >> 6;
    #pragma unroll
    for (int jj = 0; jj < 8; ++jj) {
        float v2 = val[jj] * val[jj];
        #pragma unroll
        for (int m = 1; m < 64; m <<= 1) v2 += __shfl_xor(v2, m);
        if ((tid & 63) == 0) red[wv][jj] = v2;
    }
    __syncthreads();
    const int wb = (tid >> 7) * 2;
    #pragma unroll
    for (int jj = 0; jj < 8; ++jj) {
        int c = tid + 256 * jj;
        float ss   = red[wb][jj] + red[wb + 1][jj];
        float mean = ss * (1.0f / 128.0f);
        float sc   = rsqrtf(mean + 1e-5f) * onorm_w[c & 127];
        float g    = sigmoidf_(gate[row + c]);
        outp[row + c] = (bf16)(val[jj] * sc * g);
    }
}

// ---------------------------------------------------------------------------
extern "C" void kernel_launch(void* const* d_in, const int* in_sizes, int n_in,
                              void* d_out, int out_size, void* d_ws, size_t ws_size,
                              hipStream_t stream) {
    const float* x       = (const float*)d_in[0];
    const float* Wq      = (const float*)d_in[1];
    const float* Wk      = (const float*)d_in[2];
    const float* Wv      = (const float*)d_in[3];
    const float* conv_wq = (const float*)d_in[4];
    const float* conv_wk = (const float*)d_in[5];
    const float* conv_wv = (const float*)d_in[6];
    const float* Wgb1    = (const float*)d_in[7];
    const float* Wgb2    = (const float*)d_in[8];
    const float* Wgd1    = (const float*)d_in[9];
    const float* Wgd2    = (const float*)d_in[10];
    const float* Wbb     = (const float*)d_in[11];
    const float* Wbd     = (const float*)d_in[12];
    const float* Wlam    = (const float*)d_in[13];
    const float* A_log   = (const float*)d_in[14];
    const float* dt_bias = (const float*)d_in[15];
    const float* Wg1     = (const float*)d_in[16];
    const float* Wg2     = (const float*)d_in[17];
    const float* bg2     = (const float*)d_in[18];
    const float* onorm_w = (const float*)d_in[19];
    const float* Wo      = (const float*)d_in[20];
    float* out = (float*)d_out;

    const size_t M = (size_t)B_ * T_;   // 2048

    float* ws = (float*)d_ws;
    size_t off = 0;
    auto alloc = [&](size_t nfloats) { float* p = ws + off; off += nfloats; return p; };

    float* bufQKV  = alloc(M * 6528);              // mega preacts; later gfgs+gate
    float* wqkvTf  = alloc((size_t)6528 * HID_ / 2);  // [6528,2048] bf16 (full)
    float* wextraf = alloc(((size_t)4096 * 256 + 2048 * 128 + (size_t)2048 * 2048) / 2);
                                                   // wcat + wgate + woT (own region!)
    float* xbf    = alloc(M * HID_ / 2);          // x bf16; later obf
    float* bufQ   = alloc(M * HID_);              // q fp32
    float* bufK   = alloc(M * HID_);              // k fp32
    float* bufV   = alloc(M * HID_);              // v fp32
    float* bufC   = alloc(M * HID_);              // o_f
    float* bufD   = alloc(M * HID_);              // o_s
    float* midbf  = alloc(M * 384 / 2);           // midb bf16
    float* bb     = alloc(M * H_);
    float* bd     = alloc(M * H_);
    float* lamp   = alloc(M * H_);

    bf16* xb    = (bf16*)xbf;
    bf16* obf   = (bf16*)xbf;                     // reuse after mega-gemm
    bf16* wqkvT = (bf16*)wqkvTf;
    bf16* wcat  = (bf16*)wextraf;                 // [4096,256]
    bf16* wgate = wcat + (size_t)4096 * 256;      // [2048,128]
    bf16* woT   = wgate + (size_t)2048 * 128;     // [2048,2048]
    bf16* midb  = (bf16*)midbf;
    float* gfgs = bufQKV;                         // [2048,4096] after conv
    float* bufE = bufQKV + M * 4096;              // gate [2048,2048]

    dim3 blk(256);
    auto gemm = [&](const bf16* A, const bf16* Bt, const float* bias, void* C,
                    int Mm, int Nn, int Kk, int lda, int ldc,
                    const float* alog, const float* dtb, int depi) {
        dim3 grid(Nn / 128, Mm / 128);
        mfma_gemm_kernel<<<grid, blk, 0, stream>>>(A, Bt, bias, C, Mm, Nn, Kk,
                                                   lda, ldc, alog, dtb, depi);
    };

    // 1) ALL preprocessing in one launch: x-cast, 12 transpose-casts, skinny3
    prep_kernel<<<dim3(20608), blk, 0, stream>>>(
        x, xb, Wq, Wk, Wv, Wgb1, Wgd1, Wg1, Wg2, Wo, Wgb2, Wgd2,
        wqkvT, wgate, woT, wcat, Wbb, Wbd, Wlam, bb, bd, lamp);

    // 2) mega projection: [Wq|Wk|Wv|Wgb1|Wgd1|Wg1], N=6528
    gemm(xb, wqkvT, nullptr, bufQKV, (int)M, 6528, HID_, HID_, 6528,
         nullptr, nullptr, 0);

    // 3) conv+silu(+l2norm) for q/k/v + midcast, one launch
    convmid_kernel<<<dim3(6912), blk, 0, stream>>>(
        bufQKV, conv_wq, conv_wk, conv_wv, bufQ, bufK, bufV, midb);

    // 4) gf/gs expand (N=4096, K=256) with fused decay-gate epilogue
    gemm(midb, wcat, nullptr, gfgs, (int)M, 4096, 256, 384, 4096,
         A_log, dt_bias, 1);

    // 5) gate GEMM (N=2048, K=128) + bias
    gemm(midb + 256, wgate, bg2, bufE, (int)M, HID_, 128, 384, HID_,
         nullptr, nullptr, 0);

    // 6) dual-state delta-rule recurrence (512 blocks x 256 threads)
    fkda_kernel<<<dim3(512), blk, 0, stream>>>(bufQ, bufK, bufV,
        gfgs, gfgs + 2048, 4096, bb, bd, bufC, bufD);

    // 7) mix + rmsnorm + gate -> bf16
    mix_norm_gate_kernel<<<dim3(B_ * T_), blk, 0, stream>>>(
        bufC, bufD, lamp, bufE, onorm_w, obf);

    // 8) output projection
    gemm(obf, woT, nullptr, out, (int)M, HID_, HID_, HID_, HID_,
         nullptr, nullptr, 0);
}